// Round 9
// baseline (405.696 us; speedup 1.0000x reference)
//
#include <hip/hip_runtime.h>
#include <cstdint>
#include <cstddef>

typedef _Float16 f16;
typedef f16 f16x8 __attribute__((ext_vector_type(8)));
typedef float f32x4 __attribute__((ext_vector_type(4)));
typedef float f32x2 __attribute__((ext_vector_type(2)));

#define L2E 1.44269504088896340736f

static __device__ __forceinline__ uint32_t pack2(float a, float b){
  union { f16 h[2]; uint32_t u; } t;
  t.h[0] = (f16)a; t.h[1] = (f16)b;
  return t.u;
}

static __device__ __forceinline__ f16x8 frag2(uint32_t u0, uint32_t u1){
  union { uint32_t u[4]; f16x8 v; } t;
  t.u[0] = u0; t.u[1] = u1; t.u[2] = 0u; t.u[3] = 0u;
  return t.v;
}

// ws layout (uint32 units):
//   [0, 8192)      LSTM W_hh chunks 0,1 : [tile16][chunk2][lane64][reg4]
//   [8192, 8704)   LSTM ext chunk       : [tile16][lane16][2]  (Wih*s pair, bias*s)
//   [8704, 11776)  fc1_w1 (+b1)         : [tile4][chunk3][lane64][reg4]
//   [11776, 14848) fc1_w2 (+b2)
//   [14848, 17920) fo_w1  (+b1)
//   [17920, 18688) fo_w2  (+b2)         : [tile1][chunk3][lane64][reg4]
__global__ void prep_kernel(const float* __restrict__ Wih, const float* __restrict__ Whh,
                            const float* __restrict__ bih, const float* __restrict__ bhh,
                            const float* __restrict__ w1, const float* __restrict__ B1,
                            const float* __restrict__ w2, const float* __restrict__ B2,
                            const float* __restrict__ w3, const float* __restrict__ B3,
                            const float* __restrict__ w4, const float* __restrict__ B4,
                            uint32_t* __restrict__ ws){
  int idx = blockIdx.x*256 + threadIdx.x;
  if (idx >= 18688) return;
  if (idx < 8192){
    int reg = idx & 3, ln = (idx>>2)&63, tc = idx>>8;
    int chunk = tc & 1, tile = tc >> 1;
    int j = tile*16 + (ln & 15);
    int kb = chunk*32 + (ln>>4)*8 + reg*2;
    float s = (j >= 128 && j < 192) ? 2.0f*L2E : L2E;
    ws[idx] = pack2(Whh[j*64+kb]*s, Whh[j*64+kb+1]*s);
  } else if (idx < 8704){
    int l = idx - 8192;
    int e = l & 1, ln = (l>>1)&15, tile = l>>5;
    int j = tile*16 + ln;
    float s = (j >= 128 && j < 192) ? 2.0f*L2E : L2E;
    float v0, v1;
    if (e == 0){ v0 = Wih[j*2]*s; v1 = Wih[j*2+1]*s; }
    else       { v0 = (bih[j]+bhh[j])*s; v1 = 0.f; }
    ws[idx] = pack2(v0, v1);
  } else {
    int l = idx - 8704;
    const float *W, *Bv; int nj;
    if (l < 3072)      { W=w1; Bv=B1; nj=64; }
    else if (l < 6144) { W=w2; Bv=B2; nj=64; l -= 3072; }
    else if (l < 9216) { W=w3; Bv=B3; nj=64; l -= 6144; }
    else               { W=w4; Bv=B4; nj=2;  l -= 9216; }
    int reg = l & 3, ln = (l>>2)&63, tc = l>>8;
    int chunk = tc % 3, tile = tc / 3;
    int j = tile*16 + (ln & 15);
    int kb = chunk*32 + (ln>>4)*8 + reg*2;
    float v0 = 0.f, v1 = 0.f;
    if (j < nj){
      int k0 = kb, k1 = kb+1;
      v0 = (k0 < 64) ? W[j*64+k0] : ((k0==64) ? Bv[j] : 0.f);
      v1 = (k1 < 64) ? W[j*64+k1] : ((k1==64) ? Bv[j] : 0.f);
    }
    ws[idx] = pack2(v0, v1);
  }
}

// 256 blocks x 512 threads; wave = 16 batch rows; 8 waves/block.
// Zero main-loop barriers; zero main-loop global loads (validated R8:
// FETCH 9MB / WRITE 23MB).
// R8 bottleneck: LDS pipe (8 waves x 34 ds_read_b128/step = 3200 cyc/CU/step
// > trans 2560 > MFMA 1900). Fix: W_hh lives in AGPRs — gfx950 MFMA reads
// AGPR operands directly (unified file, AV operand class), and the AGPR file
// is outside the 128-arch-VGPR cap that spilled R3-R5's register arrays.
// Pin via asm "=a" constraint (CK-style). LDS per step drops 34->2 b128.
__global__ void __launch_bounds__(512)
lstm_main(const float* __restrict__ x, const uint32_t* __restrict__ ws,
          float* __restrict__ out, const int* __restrict__ olp){
  __shared__ __attribute__((aligned(16))) uint32_t WS[9984];   // 39.9 KB: FC weights only
  __shared__ __attribute__((aligned(16))) f16 sball[24576];    // 48 KB: h | y1 | y2 (per-wave 1024 halves each)
  __shared__ uint32_t xb[8][16][8];                            // packed fp16 (x0,x1); slot7 = last
  __shared__ float lastb[8][16][2];                            // fp32 carry "last"

  const int tid  = threadIdx.x;
  const int lane = tid & 63;
  const int wave = tid >> 6;
  const int c0   = lane & 15;     // A row / C col / B col within tile
  const int hi   = lane >> 4;     // k-group (A/B), row-group (C)
  const int batch0 = blockIdx.x*128 + wave*16;
  const int OL = olp[0];
  const int ostride = OL*2;

  const int hbase  = wave*1024;          // halves
  const int y1base = 8192  + wave*1024;
  const int y2base = 16384 + wave*1024;

  // ---- stage FC weights to LDS + wave-private init (single barrier) ----
  for (int i = tid; i < 9984; i += 512) WS[i] = ws[8704 + i];
  *(f16x8*)&sball[hbase + lane*16]     = (f16x8)(f16)0.f;      // h0 = 0
  *(f16x8*)&sball[hbase + lane*16 + 8] = (f16x8)(f16)0.f;
  if (hi == 0){
    const float* xp = x + (size_t)(batch0 + c0)*16;
    #pragma unroll
    for (int t = 0; t < 8; ++t){
      float a = xp[2*t], b = xp[2*t+1];
      xb[wave][c0][t] = pack2(a, b);
      if (t == 7){ lastb[wave][c0][0] = a; lastb[wave][c0][1] = b; }
    }
  }

  // ---- W_hh into AGPRs (128 acc regs), straight from global (L2-hot) ----
  f16x8 Wa0[16], Wa1[16];
  #pragma unroll
  for (int T = 0; T < 16; ++T){
    f16x8 w0 = *(const f16x8*)(ws + ((size_t)(T*2+0)*64 + lane)*4);
    f16x8 w1 = *(const f16x8*)(ws + ((size_t)(T*2+1)*64 + lane)*4);
    asm("" : "=a"(Wa0[T]) : "0"(w0));   // pin to AGPR class
    asm("" : "=a"(Wa1[T]) : "0"(w1));
  }

  // ext B-frag dword pairs (32 VGPR, loop-invariant)
  uint32_t e0v[16], e1v[16];
  #pragma unroll
  for (int T = 0; T < 16; ++T){
    uint32_t a = 0u, b = 0u;
    if (hi == 0){ a = ws[8192 + (T*16 + c0)*2]; b = ws[8192 + (T*16 + c0)*2 + 1]; }
    e0v[T] = a; e1v[T] = b;
  }
  __syncthreads();

  const f32x4 zero4 = {0.f, 0.f, 0.f, 0.f};
  const f32x2 one2  = {1.f, 1.f};
  f32x2 cst[4][2];                      // c: cst[Tg][p] rows {hi*4+2p,+1}, col Tg*16+c0
  #pragma unroll
  for (int Tg = 0; Tg < 4; ++Tg){ cst[Tg][0] = (f32x2){0.f,0.f}; cst[Tg][1] = (f32x2){0.f,0.f}; }

  auto sread = [&](int base, int chunk)->f16x8{
    int bo = (c0<<7) | (chunk<<6) | (hi<<4);
    bo ^= ((c0 & 7) << 4);              // XOR swizzle: conflict-free b128
    return *(const f16x8*)&sball[base + (bo>>1)];
  };
  auto swrite = [&](int base, int brow, int j, float v){
    int bo = (((brow<<6) | j) << 1) ^ ((brow & 7) << 4);
    sball[base + (bo>>1)] = (f16)v;
  };

  const uint32_t ou1 = (hi==0) ? 0x00003C00u : 0u;   // fp16 1.0 in ext k-slot 2
  const f16x8 aone = frag2(ou1, 0u);
  // FC bases inside WS (dwords): F1=0, F2=3072, G1=6144, G2=9216
  auto fcTileL = [&](int fbase, int T, f16x8 i0, f16x8 i1)->f32x4{
    const f16x8 b0 = *(const f16x8*)&WS[fbase + ((T*3+0)*64 + lane)*4];
    const f16x8 b1 = *(const f16x8*)&WS[fbase + ((T*3+1)*64 + lane)*4];
    const f16x8 b2 = *(const f16x8*)&WS[fbase + ((T*3+2)*64 + lane)*4];
    f32x4 a = __builtin_amdgcn_mfma_f32_16x16x32_f16(i0, b0, zero4, 0,0,0);
    a = __builtin_amdgcn_mfma_f32_16x16x32_f16(i1, b1, a, 0,0,0);
    a = __builtin_amdgcn_mfma_f32_16x16x32_f16(aone, b2, a, 0,0,0);
    return a;
  };

  #pragma unroll 1
  for (int it = 0; it < OL; ++it){
    // ---- 8 LSTM steps (wave-private, barrier-free; W from AGPRs) ----
    #pragma unroll 1
    for (int t = 0; t < 8; ++t){
      f16x8 a0 = sread(hbase, 0);
      f16x8 a1 = sread(hbase, 1);
      uint32_t xu = (hi==0) ? xb[wave][c0][t] : 0u;
      f16x8 ax = frag2(xu, ou1);        // A ext: [x0, x1, 1, 0...]
      #pragma unroll
      for (int Tg = 0; Tg < 4; ++Tg){
        f32x4 za[4];                    // i, f, g, o tiles for cols Tg*16+c0
        #pragma unroll
        for (int q = 0; q < 4; ++q){
          const int T = Tg + q*4;
          f32x4 a = __builtin_amdgcn_mfma_f32_16x16x32_f16(a0, Wa0[T], zero4, 0,0,0);
          a = __builtin_amdgcn_mfma_f32_16x16x32_f16(a1, Wa1[T], a, 0,0,0);
          a = __builtin_amdgcn_mfma_f32_16x16x32_f16(ax, frag2(e0v[T], e1v[T]), a, 0,0,0);
          za[q] = a;
        }
        #pragma unroll
        for (int p = 0; p < 2; ++p){
          f32x2 zi = { za[0][2*p], za[0][2*p+1] };
          f32x2 zf = { za[1][2*p], za[1][2*p+1] };
          f32x2 zg = { za[2][2*p], za[2][2*p+1] };
          f32x2 zo = { za[3][2*p], za[3][2*p+1] };
          f32x2 ei, ef, eg, eo;
          ei.x = __builtin_amdgcn_exp2f(-zi.x); ei.y = __builtin_amdgcn_exp2f(-zi.y);
          ef.x = __builtin_amdgcn_exp2f(-zf.x); ef.y = __builtin_amdgcn_exp2f(-zf.y);
          eg.x = __builtin_amdgcn_exp2f(-zg.x); eg.y = __builtin_amdgcn_exp2f(-zg.y);
          eo.x = __builtin_amdgcn_exp2f(-zo.x); eo.y = __builtin_amdgcn_exp2f(-zo.y);
          f32x2 di = one2 + ei, df = one2 + ef, dg = one2 + eg, dd = one2 + eo;
          f32x2 si, sf, rg, so;
          si.x = __builtin_amdgcn_rcpf(di.x); si.y = __builtin_amdgcn_rcpf(di.y);
          sf.x = __builtin_amdgcn_rcpf(df.x); sf.y = __builtin_amdgcn_rcpf(df.y);
          rg.x = __builtin_amdgcn_rcpf(dg.x); rg.y = __builtin_amdgcn_rcpf(dg.y);
          so.x = __builtin_amdgcn_rcpf(dd.x); so.y = __builtin_amdgcn_rcpf(dd.y);
          f32x2 tg = 2.0f*rg - one2;                   // tanh(g)
          f32x2 cv = sf*cst[Tg][p] + si*tg;
          cst[Tg][p] = cv;
          f32x2 m  = cv * (-2.0f*L2E);
          f32x2 ec; ec.x = __builtin_amdgcn_exp2f(m.x); ec.y = __builtin_amdgcn_exp2f(m.y);
          f32x2 dc = one2 + ec;
          f32x2 tc; tc.x = __builtin_amdgcn_rcpf(dc.x); tc.y = __builtin_amdgcn_rcpf(dc.y);
          f32x2 th = 2.0f*tc - one2;                   // tanh(c)
          f32x2 hv = so*th;
          swrite(hbase, hi*4 + 2*p,     Tg*16 + c0, hv.x);
          swrite(hbase, hi*4 + 2*p + 1, Tg*16 + c0, hv.y);
        }
      }
    }

    // ---- FC head: h -> y1 -> y2 -> y1 -> out (per-tile immediate writes,
    //      WAR-safe: same-wave DS ops execute in order) ----
    {
      f16x8 i0 = sread(hbase, 0), i1 = sread(hbase, 1);
      #pragma unroll
      for (int T = 0; T < 4; ++T){
        f32x4 y = fcTileL(0, T, i0, i1);
        #pragma unroll
        for (int rr = 0; rr < 4; ++rr){
          float v = y[rr];
          v = fmaxf(v, 0.1f*v);         // leaky
          swrite(y1base, hi*4+rr, T*16+c0, v);
        }
      }
    }
    {
      f16x8 i0 = sread(y1base, 0), i1 = sread(y1base, 1);
      #pragma unroll
      for (int T = 0; T < 4; ++T){
        f32x4 y = fcTileL(3072, T, i0, i1);
        #pragma unroll
        for (int rr = 0; rr < 4; ++rr)
          swrite(y2base, hi*4+rr, T*16+c0, y[rr]);     // no activation
      }
    }
    {
      f16x8 i0 = sread(y2base, 0), i1 = sread(y2base, 1);
      #pragma unroll
      for (int T = 0; T < 4; ++T){
        f32x4 y = fcTileL(6144, T, i0, i1);
        #pragma unroll
        for (int rr = 0; rr < 4; ++rr){
          float v = y[rr];
          v = fmaxf(v, 0.1f*v);         // leaky
          swrite(y1base, hi*4+rr, T*16+c0, v);
        }
      }
    }
    {
      f16x8 i0 = sread(y1base, 0), i1 = sread(y1base, 1);
      f32x4 o = fcTileL(9216, 0, i0, i1);   // only cols 0,1 valid
      if (c0 < 2){
        #pragma unroll
        for (int rr = 0; rr < 4; ++rr){
          int brow = hi*4 + rr;
          float v = o[rr];
          out[(size_t)(batch0 + brow)*ostride + it*2 + c0] = v;
          lastb[wave][brow][c0] += v;
        }
      }
    }
    if (hi == 0){
      xb[wave][c0][7] = pack2(lastb[wave][c0][0], lastb[wave][c0][1]);
    }
  }
}

extern "C" void kernel_launch(void* const* d_in, const int* in_sizes, int n_in,
                              void* d_out, int out_size, void* d_ws, size_t ws_size,
                              hipStream_t stream){
  const float* x    = (const float*)d_in[0];
  const float* Wih  = (const float*)d_in[2];
  const float* Whh  = (const float*)d_in[3];
  const float* bih  = (const float*)d_in[4];
  const float* bhh  = (const float*)d_in[5];
  const float* f1w1 = (const float*)d_in[6];
  const float* f1b1 = (const float*)d_in[7];
  const float* f1w2 = (const float*)d_in[8];
  const float* f1b2 = (const float*)d_in[9];
  const float* fow1 = (const float*)d_in[10];
  const float* fob1 = (const float*)d_in[11];
  const float* fow2 = (const float*)d_in[12];
  const float* fob2 = (const float*)d_in[13];
  const int*   olp  = (const int*)d_in[14];
  uint32_t* ws = (uint32_t*)d_ws;

  hipLaunchKernelGGL(prep_kernel, dim3(73), dim3(256), 0, stream,
                     Wih, Whh, bih, bhh, f1w1, f1b1, f1w2, f1b2,
                     fow1, fob1, fow2, fob2, ws);
  hipLaunchKernelGGL(lstm_main, dim3(256), dim3(512), 0, stream,
                     x, ws, (float*)d_out, olp);
}

// Round 10
// 344.892 us; speedup vs baseline: 1.1763x; 1.1763x over previous
//
#include <hip/hip_runtime.h>
#include <cstdint>
#include <cstddef>

typedef _Float16 f16;
typedef f16 f16x8 __attribute__((ext_vector_type(8)));
typedef float f32x4 __attribute__((ext_vector_type(4)));
typedef float f32x2 __attribute__((ext_vector_type(2)));

#define L2E 1.44269504088896340736f

static __device__ __forceinline__ uint32_t pack2(float a, float b){
  union { f16 h[2]; uint32_t u; } t;
  t.h[0] = (f16)a; t.h[1] = (f16)b;
  return t.u;
}

static __device__ __forceinline__ f16x8 frag2(uint32_t u0, uint32_t u1){
  union { uint32_t u[4]; f16x8 v; } t;
  t.u[0] = u0; t.u[1] = u1; t.u[2] = 0u; t.u[3] = 0u;
  return t.v;
}

// ws layout (uint32 units):
//   [0, 8192)      LSTM W_hh chunks 0,1 : [tile16][chunk2][lane64][reg4]
//   [8192, 8704)   LSTM ext chunk       : [tile16][lane16][2]  (Wih*s pair, bias*s)
//   [8704, 11776)  fc1_w1 (+b1)         : [tile4][chunk3][lane64][reg4]
//   [11776, 14848) fc1_w2 (+b2)
//   [14848, 17920) fo_w1  (+b1)
//   [17920, 18688) fo_w2  (+b2)         : [tile1][chunk3][lane64][reg4]
__global__ void prep_kernel(const float* __restrict__ Wih, const float* __restrict__ Whh,
                            const float* __restrict__ bih, const float* __restrict__ bhh,
                            const float* __restrict__ w1, const float* __restrict__ B1,
                            const float* __restrict__ w2, const float* __restrict__ B2,
                            const float* __restrict__ w3, const float* __restrict__ B3,
                            const float* __restrict__ w4, const float* __restrict__ B4,
                            uint32_t* __restrict__ ws){
  int idx = blockIdx.x*256 + threadIdx.x;
  if (idx >= 18688) return;
  if (idx < 8192){
    int reg = idx & 3, ln = (idx>>2)&63, tc = idx>>8;
    int chunk = tc & 1, tile = tc >> 1;
    int j = tile*16 + (ln & 15);
    int kb = chunk*32 + (ln>>4)*8 + reg*2;
    float s = (j >= 128 && j < 192) ? 2.0f*L2E : L2E;
    ws[idx] = pack2(Whh[j*64+kb]*s, Whh[j*64+kb+1]*s);
  } else if (idx < 8704){
    int l = idx - 8192;
    int e = l & 1, ln = (l>>1)&15, tile = l>>5;
    int j = tile*16 + ln;
    float s = (j >= 128 && j < 192) ? 2.0f*L2E : L2E;
    float v0, v1;
    if (e == 0){ v0 = Wih[j*2]*s; v1 = Wih[j*2+1]*s; }
    else       { v0 = (bih[j]+bhh[j])*s; v1 = 0.f; }
    ws[idx] = pack2(v0, v1);
  } else {
    int l = idx - 8704;
    const float *W, *Bv; int nj;
    if (l < 3072)      { W=w1; Bv=B1; nj=64; }
    else if (l < 6144) { W=w2; Bv=B2; nj=64; l -= 3072; }
    else if (l < 9216) { W=w3; Bv=B3; nj=64; l -= 6144; }
    else               { W=w4; Bv=B4; nj=2;  l -= 9216; }
    int reg = l & 3, ln = (l>>2)&63, tc = l>>8;
    int chunk = tc % 3, tile = tc / 3;
    int j = tile*16 + (ln & 15);
    int kb = chunk*32 + (ln>>4)*8 + reg*2;
    float v0 = 0.f, v1 = 0.f;
    if (j < nj){
      int k0 = kb, k1 = kb+1;
      v0 = (k0 < 64) ? W[j*64+k0] : ((k0==64) ? Bv[j] : 0.f);
      v1 = (k1 < 64) ? W[j*64+k1] : ((k1==64) ? Bv[j] : 0.f);
    }
    ws[idx] = pack2(v0, v1);
  }
}

// 256 blocks x 512 threads; wave = 16 batch rows; 8 waves/block.
// R8 base (302us, FETCH 9MB / WRITE 23MB): zero main-loop barriers, zero
// main-loop global loads, all weights in LDS. R9 negative result: LDS reads
// are hidden (AGPR-caching W made it SLOWER via accvgpr-copy VALU ops).
// R8 profile: VALU-busy 183us + MFMA 75us = 85% of wall -> pipes barely
// overlap because same-code waves stay phase-locked. This round:
//  (a) anti-phase stagger: waves 4-7 (SIMD partners of 0-3 under w%4
//      round-robin) sleep ~2560cyc once; barrier-free loop preserves offset
//  (b) s_setprio(1) around the LSTM MFMA cluster (T5; independent waves)
__global__ void __launch_bounds__(512)
lstm_main(const float* __restrict__ x, const uint32_t* __restrict__ ws,
          float* __restrict__ out, const int* __restrict__ olp){
  __shared__ __attribute__((aligned(16))) uint32_t WS[18176];  // 72.7 KB: [0,8192)=W_hh, [8192,18176)=FC
  __shared__ __attribute__((aligned(16))) f16 sball[24576];    // 48 KB: h | y1 | y2 (per-wave 1024 halves each)
  __shared__ uint32_t xb[8][16][8];                            // packed fp16 (x0,x1); slot7 = last
  __shared__ float lastb[8][16][2];                            // fp32 carry "last"

  const int tid  = threadIdx.x;
  const int lane = tid & 63;
  const int wave = tid >> 6;
  const int c0   = lane & 15;     // A row / C col / B col within tile
  const int hi   = lane >> 4;     // k-group (A/B), row-group (C)
  const int batch0 = blockIdx.x*128 + wave*16;
  const int OL = olp[0];
  const int ostride = OL*2;

  const int hbase  = wave*1024;          // halves
  const int y1base = 8192  + wave*1024;
  const int y2base = 16384 + wave*1024;

  // ---- stage ALL weights to LDS + wave-private init (single barrier) ----
  for (int i = tid; i < 18176; i += 512)
    WS[i] = ws[i < 8192 ? i : i + 512];          // skip ext chunk (goes to regs)
  *(f16x8*)&sball[hbase + lane*16]     = (f16x8)(f16)0.f;      // h0 = 0
  *(f16x8*)&sball[hbase + lane*16 + 8] = (f16x8)(f16)0.f;
  if (hi == 0){
    const float* xp = x + (size_t)(batch0 + c0)*16;
    #pragma unroll
    for (int t = 0; t < 8; ++t){
      float a = xp[2*t], b = xp[2*t+1];
      xb[wave][c0][t] = pack2(a, b);
      if (t == 7){ lastb[wave][c0][0] = a; lastb[wave][c0][1] = b; }
    }
  }

  // ext B-frag dword pairs from GLOBAL (pre-barrier, loop-invariant, 32 VGPR)
  uint32_t e0v[16], e1v[16];
  #pragma unroll
  for (int T = 0; T < 16; ++T){
    uint32_t a = 0u, b = 0u;
    if (hi == 0){ a = ws[8192 + (T*16 + c0)*2]; b = ws[8192 + (T*16 + c0)*2 + 1]; }
    e0v[T] = a; e1v[T] = b;
  }
  __syncthreads();

  // ---- anti-phase stagger: SIMD partner waves offset by ~half a step ----
  if (wave & 4) __builtin_amdgcn_s_sleep(40);   // ~2560 cycles, one-time

  const f32x4 zero4 = {0.f, 0.f, 0.f, 0.f};
  const f32x2 one2  = {1.f, 1.f};
  f32x2 cst[4][2];                      // c: cst[Tg][p] rows {hi*4+2p,+1}, col Tg*16+c0
  #pragma unroll
  for (int Tg = 0; Tg < 4; ++Tg){ cst[Tg][0] = (f32x2){0.f,0.f}; cst[Tg][1] = (f32x2){0.f,0.f}; }

  auto sread = [&](int base, int chunk)->f16x8{
    int bo = (c0<<7) | (chunk<<6) | (hi<<4);
    bo ^= ((c0 & 7) << 4);              // XOR swizzle: conflict-free b128
    return *(const f16x8*)&sball[base + (bo>>1)];
  };
  auto swrite = [&](int base, int brow, int j, float v){
    int bo = (((brow<<6) | j) << 1) ^ ((brow & 7) << 4);
    sball[base + (bo>>1)] = (f16)v;
  };

  const uint32_t ou1 = (hi==0) ? 0x00003C00u : 0u;   // fp16 1.0 in ext k-slot 2
  const f16x8 aone = frag2(ou1, 0u);
  // FC bases inside WS (dwords): F1=8192, F2=11264, G1=14336, G2=17408
  auto fcTileL = [&](int fbase, int T, f16x8 i0, f16x8 i1)->f32x4{
    const f16x8 b0 = *(const f16x8*)&WS[fbase + ((T*3+0)*64 + lane)*4];
    const f16x8 b1 = *(const f16x8*)&WS[fbase + ((T*3+1)*64 + lane)*4];
    const f16x8 b2 = *(const f16x8*)&WS[fbase + ((T*3+2)*64 + lane)*4];
    f32x4 a = __builtin_amdgcn_mfma_f32_16x16x32_f16(i0, b0, zero4, 0,0,0);
    a = __builtin_amdgcn_mfma_f32_16x16x32_f16(i1, b1, a, 0,0,0);
    a = __builtin_amdgcn_mfma_f32_16x16x32_f16(aone, b2, a, 0,0,0);
    return a;
  };

  #pragma unroll 1
  for (int it = 0; it < OL; ++it){
    // ---- 8 LSTM steps (wave-private, barrier-free, LDS-only) ----
    #pragma unroll 1
    for (int t = 0; t < 8; ++t){
      f16x8 a0 = sread(hbase, 0);
      f16x8 a1 = sread(hbase, 1);
      uint32_t xu = (hi==0) ? xb[wave][c0][t] : 0u;
      f16x8 ax = frag2(xu, ou1);        // A ext: [x0, x1, 1, 0...]
      #pragma unroll
      for (int Tg = 0; Tg < 4; ++Tg){
        f32x4 za[4];                    // i, f, g, o tiles for cols Tg*16+c0
        __builtin_amdgcn_s_setprio(1);
        #pragma unroll
        for (int q = 0; q < 4; ++q){
          const int T = Tg + q*4;
          const f16x8 b0 = *(const f16x8*)&WS[((T*2+0)*64 + lane)*4];
          const f16x8 b1 = *(const f16x8*)&WS[((T*2+1)*64 + lane)*4];
          f32x4 a = __builtin_amdgcn_mfma_f32_16x16x32_f16(a0, b0, zero4, 0,0,0);
          a = __builtin_amdgcn_mfma_f32_16x16x32_f16(a1, b1, a, 0,0,0);
          a = __builtin_amdgcn_mfma_f32_16x16x32_f16(ax, frag2(e0v[T], e1v[T]), a, 0,0,0);
          za[q] = a;
        }
        __builtin_amdgcn_s_setprio(0);
        #pragma unroll
        for (int p = 0; p < 2; ++p){
          f32x2 zi = { za[0][2*p], za[0][2*p+1] };
          f32x2 zf = { za[1][2*p], za[1][2*p+1] };
          f32x2 zg = { za[2][2*p], za[2][2*p+1] };
          f32x2 zo = { za[3][2*p], za[3][2*p+1] };
          f32x2 ei, ef, eg, eo;
          ei.x = __builtin_amdgcn_exp2f(-zi.x); ei.y = __builtin_amdgcn_exp2f(-zi.y);
          ef.x = __builtin_amdgcn_exp2f(-zf.x); ef.y = __builtin_amdgcn_exp2f(-zf.y);
          eg.x = __builtin_amdgcn_exp2f(-zg.x); eg.y = __builtin_amdgcn_exp2f(-zg.y);
          eo.x = __builtin_amdgcn_exp2f(-zo.x); eo.y = __builtin_amdgcn_exp2f(-zo.y);
          f32x2 di = one2 + ei, df = one2 + ef, dg = one2 + eg, dd = one2 + eo;
          f32x2 si, sf, rg, so;
          si.x = __builtin_amdgcn_rcpf(di.x); si.y = __builtin_amdgcn_rcpf(di.y);
          sf.x = __builtin_amdgcn_rcpf(df.x); sf.y = __builtin_amdgcn_rcpf(df.y);
          rg.x = __builtin_amdgcn_rcpf(dg.x); rg.y = __builtin_amdgcn_rcpf(dg.y);
          so.x = __builtin_amdgcn_rcpf(dd.x); so.y = __builtin_amdgcn_rcpf(dd.y);
          f32x2 tg = 2.0f*rg - one2;                   // tanh(g)
          f32x2 cv = sf*cst[Tg][p] + si*tg;
          cst[Tg][p] = cv;
          f32x2 m  = cv * (-2.0f*L2E);
          f32x2 ec; ec.x = __builtin_amdgcn_exp2f(m.x); ec.y = __builtin_amdgcn_exp2f(m.y);
          f32x2 dc = one2 + ec;
          f32x2 tc; tc.x = __builtin_amdgcn_rcpf(dc.x); tc.y = __builtin_amdgcn_rcpf(dc.y);
          f32x2 th = 2.0f*tc - one2;                   // tanh(c)
          f32x2 hv = so*th;
          swrite(hbase, hi*4 + 2*p,     Tg*16 + c0, hv.x);
          swrite(hbase, hi*4 + 2*p + 1, Tg*16 + c0, hv.y);
        }
      }
    }

    // ---- FC head: h -> y1 -> y2 -> y1 -> out (per-tile immediate writes,
    //      WAR-safe: same-wave DS ops execute in order) ----
    {
      f16x8 i0 = sread(hbase, 0), i1 = sread(hbase, 1);
      #pragma unroll
      for (int T = 0; T < 4; ++T){
        f32x4 y = fcTileL(8192, T, i0, i1);
        #pragma unroll
        for (int rr = 0; rr < 4; ++rr){
          float v = y[rr];
          v = fmaxf(v, 0.1f*v);         // leaky
          swrite(y1base, hi*4+rr, T*16+c0, v);
        }
      }
    }
    {
      f16x8 i0 = sread(y1base, 0), i1 = sread(y1base, 1);
      #pragma unroll
      for (int T = 0; T < 4; ++T){
        f32x4 y = fcTileL(11264, T, i0, i1);
        #pragma unroll
        for (int rr = 0; rr < 4; ++rr)
          swrite(y2base, hi*4+rr, T*16+c0, y[rr]);     // no activation
      }
    }
    {
      f16x8 i0 = sread(y2base, 0), i1 = sread(y2base, 1);
      #pragma unroll
      for (int T = 0; T < 4; ++T){
        f32x4 y = fcTileL(14336, T, i0, i1);
        #pragma unroll
        for (int rr = 0; rr < 4; ++rr){
          float v = y[rr];
          v = fmaxf(v, 0.1f*v);         // leaky
          swrite(y1base, hi*4+rr, T*16+c0, v);
        }
      }
    }
    {
      f16x8 i0 = sread(y1base, 0), i1 = sread(y1base, 1);
      f32x4 o = fcTileL(17408, 0, i0, i1);   // only cols 0,1 valid
      if (c0 < 2){
        #pragma unroll
        for (int rr = 0; rr < 4; ++rr){
          int brow = hi*4 + rr;
          float v = o[rr];
          out[(size_t)(batch0 + brow)*ostride + it*2 + c0] = v;
          lastb[wave][brow][c0] += v;
        }
      }
    }
    if (hi == 0){
      xb[wave][c0][7] = pack2(lastb[wave][c0][0], lastb[wave][c0][1]);
    }
  }
}

extern "C" void kernel_launch(void* const* d_in, const int* in_sizes, int n_in,
                              void* d_out, int out_size, void* d_ws, size_t ws_size,
                              hipStream_t stream){
  const float* x    = (const float*)d_in[0];
  const float* Wih  = (const float*)d_in[2];
  const float* Whh  = (const float*)d_in[3];
  const float* bih  = (const float*)d_in[4];
  const float* bhh  = (const float*)d_in[5];
  const float* f1w1 = (const float*)d_in[6];
  const float* f1b1 = (const float*)d_in[7];
  const float* f1w2 = (const float*)d_in[8];
  const float* f1b2 = (const float*)d_in[9];
  const float* fow1 = (const float*)d_in[10];
  const float* fob1 = (const float*)d_in[11];
  const float* fow2 = (const float*)d_in[12];
  const float* fob2 = (const float*)d_in[13];
  const int*   olp  = (const int*)d_in[14];
  uint32_t* ws = (uint32_t*)d_ws;

  hipLaunchKernelGGL(prep_kernel, dim3(73), dim3(256), 0, stream,
                     Wih, Whh, bih, bhh, f1w1, f1b1, f1w2, f1b2,
                     fow1, fob1, fow2, fob2, ws);
  hipLaunchKernelGGL(lstm_main, dim3(256), dim3(512), 0, stream,
                     x, ws, (float*)d_out, olp);
}